// Round 2
// baseline (988.054 us; speedup 1.0000x reference)
//
#include <hip/hip_runtime.h>
#include <hip/hip_bf16.h>
#include <math.h>

#define S_LEN 2048
#define DHEAD 128
#define NH    32          // B*H
#define BM    64          // q rows per workgroup
#define KT    64          // kv rows per tile
#define NKT   (S_LEN / KT)
#define SCALE 0.08838834764831845f   // 1/sqrt(128)

typedef __attribute__((ext_vector_type(4))) float f32x4;
typedef __attribute__((ext_vector_type(8))) unsigned short u16x8;
typedef __attribute__((ext_vector_type(4))) unsigned short u16x4;
typedef __attribute__((ext_vector_type(8))) __bf16 bf16x8;

static __device__ __forceinline__ unsigned short bfr(float x) {
  __bf16 h = (__bf16)x;                       // v_cvt RNE
  return __builtin_bit_cast(unsigned short, h);
}
static __device__ __forceinline__ float bup(unsigned short h) {
  return (float)__builtin_bit_cast(__bf16, h);
}
static __device__ __forceinline__ bf16x8 as_bf(u16x8 x) {
  return __builtin_bit_cast(bf16x8, x);
}

__global__ __launch_bounds__(256, 3) void attn_kernel(
    const float* __restrict__ Qg, const float* __restrict__ Kg,
    const float* __restrict__ Vg, float* __restrict__ out) {
  __shared__ unsigned short khi[KT * DHEAD];   // 16 KB
  __shared__ unsigned short klo[KT * DHEAD];   // 16 KB (P-bf16 buffer aliases low 8 KB)
  __shared__ unsigned short vtr[DHEAD * KT];   // 16 KB (V transposed)
  // total 48 KB -> 3 blocks/CU

  const int tid = threadIdx.x;
  const int w  = tid >> 6;
  const int l  = tid & 63;
  const int lr = l & 15;   // lane row
  const int lg = l >> 4;   // lane group

  // XCD-aware decode: all 32 q-blocks of a head on the same XCD (dispatch%8).
  const int d_  = blockIdx.x;          // 0..1023
  const int xcd = d_ & 7;
  const int slot = d_ >> 3;            // 0..127
  const int bh = xcd + 8 * (slot >> 5);
  const int qb = slot & 31;

  const size_t head_off = (size_t)bh * S_LEN * DHEAD;
  const float* Qh = Qg + head_off;
  const float* Kh = Kg + head_off;
  const float* Vh = Vg + head_off;
  float* Ov = out + head_off;
  float* Pa = out + (size_t)NH * S_LEN * DHEAD + (size_t)bh * S_LEN * S_LEN;

  // per-thread staging coordinates (constant across tiles)
  // K: idx4 = p*256+tid -> kv = idx4>>5, d4 = idx4&31
  // V: kv = (idx4>>2)&63, d4 = (idx4&3)|((idx4>>8)<<2)

  float4 kx[8], vx[8];

  // ---- prologue: issue K tile-0 loads, then build Q fragments ----
  {
    const float4* s4 = (const float4*)Kh;
#pragma unroll
    for (int p = 0; p < 8; ++p) kx[p] = s4[p * 256 + tid];
  }

  const int qrow = qb * BM + w * 16 + lr;
  const float* qptr = Qh + (size_t)qrow * DHEAD;
  u16x8 qh[4], qlo[4];
#pragma unroll
  for (int kc = 0; kc < 4; ++kc) {
    const float4* qp4 = (const float4*)(qptr + kc * 32 + lg * 8);
    float4 a = qp4[0], b = qp4[1];
    float xs[8] = {a.x, a.y, a.z, a.w, b.x, b.y, b.z, b.w};
#pragma unroll
    for (int i = 0; i < 8; ++i) {
      float x = xs[i] * SCALE;
      unsigned short h = bfr(x);
      qh[kc][i] = h;
      qlo[kc][i] = bfr(x - bup(h));
    }
  }

  const f32x4 zero4 = {0.f, 0.f, 0.f, 0.f};
  float m = -INFINITY, lsum = 0.f;

  // ================= phase 1: running row max & sum (hi-only QK) ===========
  for (int kt = 0; kt < NKT; ++kt) {
    __syncthreads();                       // prev-iter khi reads done
    // convert + write khi from kx
#pragma unroll
    for (int p = 0; p < 8; ++p) {
      int idx4 = p * 256 + tid, kv = idx4 >> 5, d4 = idx4 & 31;
      float f[4] = {kx[p].x, kx[p].y, kx[p].z, kx[p].w};
      u16x4 hi;
#pragma unroll
      for (int j = 0; j < 4; ++j) hi[j] = bfr(f[j]);
      *(u16x4*)&khi[kv * 128 + ((d4 * 4) ^ ((kv & 7) << 3))] = hi;
    }
    // prefetch next tile (or phase-2 tile 0 K+V at the last iteration)
    if (kt + 1 < NKT) {
      const float4* s4 = (const float4*)(Kh + (size_t)(kt + 1) * KT * DHEAD);
#pragma unroll
      for (int p = 0; p < 8; ++p) kx[p] = s4[p * 256 + tid];
    } else {
      const float4* s4 = (const float4*)Kh;
      const float4* sv = (const float4*)Vh;
#pragma unroll
      for (int p = 0; p < 8; ++p) kx[p] = s4[p * 256 + tid];
#pragma unroll
      for (int p = 0; p < 8; ++p) {
        int idx4 = p * 256 + tid;
        int kv = (idx4 >> 2) & 63, d4 = (idx4 & 3) | ((idx4 >> 8) << 2);
        vx[p] = sv[kv * 32 + d4];
      }
    }
    __syncthreads();                       // staging visible

    f32x4 sacc[4];
#pragma unroll
    for (int mt = 0; mt < 4; ++mt) sacc[mt] = zero4;
    __builtin_amdgcn_s_setprio(1);
#pragma unroll
    for (int mt = 0; mt < 4; ++mt) {
      const int row = mt * 16 + lr;
      const int rbase = row * 128;
      const int sw = (row & 7) << 3;
#pragma unroll
      for (int kc = 0; kc < 4; ++kc) {
        u16x8 kf = *(const u16x8*)&khi[rbase + ((kc * 32 + lg * 8) ^ sw)];
        sacc[mt] = __builtin_amdgcn_mfma_f32_16x16x32_bf16(
            as_bf(kf), as_bf(qh[kc]), sacc[mt], 0, 0, 0);
      }
    }
    __builtin_amdgcn_s_setprio(0);

    float tmax = sacc[0][0];
#pragma unroll
    for (int mt = 0; mt < 4; ++mt)
#pragma unroll
      for (int r = 0; r < 4; ++r) tmax = fmaxf(tmax, sacc[mt][r]);
    tmax = fmaxf(tmax, __shfl_xor(tmax, 16));
    tmax = fmaxf(tmax, __shfl_xor(tmax, 32));
    float mnew = fmaxf(m, tmax);
    float esum = 0.f;
#pragma unroll
    for (int mt = 0; mt < 4; ++mt)
#pragma unroll
      for (int r = 0; r < 4; ++r) esum += __expf(sacc[mt][r] - mnew);
    esum += __shfl_xor(esum, 16);
    esum += __shfl_xor(esum, 32);
    lsum = lsum * __expf(m - mnew) + esum;
    m = mnew;
  }
  const float invl = 1.0f / lsum;

  // ================= phase 2: recompute (split), write P, PV ===============
  f32x4 oacc[8];
#pragma unroll
  for (int dt = 0; dt < 8; ++dt) oacc[dt] = zero4;

  unsigned short* pwb = klo + (w << 10);         // per-wave 16x64 bf16 (2 KB)
  float* Prow = Pa + (size_t)(qb * BM + w * 16 + lr) * S_LEN;

  for (int kt = 0; kt < NKT; ++kt) {
    __syncthreads();                       // prev-iter khi/klo/vtr/pwb reads done
    // convert + write khi/klo from kx, vtr from vx
#pragma unroll
    for (int p = 0; p < 8; ++p) {
      int idx4 = p * 256 + tid, kv = idx4 >> 5, d4 = idx4 & 31;
      float f[4] = {kx[p].x, kx[p].y, kx[p].z, kx[p].w};
      u16x4 hi, lo;
#pragma unroll
      for (int j = 0; j < 4; ++j) {
        unsigned short h = bfr(f[j]);
        hi[j] = h;
        lo[j] = bfr(f[j] - bup(h));
      }
      int off = kv * 128 + ((d4 * 4) ^ ((kv & 7) << 3));
      *(u16x4*)&khi[off] = hi;
      *(u16x4*)&klo[off] = lo;
    }
#pragma unroll
    for (int p = 0; p < 8; ++p) {
      int idx4 = p * 256 + tid;
      int kv = (idx4 >> 2) & 63, d4 = (idx4 & 3) | ((idx4 >> 8) << 2);
      float f[4] = {vx[p].x, vx[p].y, vx[p].z, vx[p].w};
#pragma unroll
      for (int j = 0; j < 4; ++j) {
        int d = d4 * 4 + j;
        vtr[d * 64 + (kv ^ ((d & 7) << 3))] = bfr(f[j]);
      }
    }
    // prefetch next K+V tiles into freed regs
    if (kt + 1 < NKT) {
      const float4* s4 = (const float4*)(Kh + (size_t)(kt + 1) * KT * DHEAD);
      const float4* sv = (const float4*)(Vh + (size_t)(kt + 1) * KT * DHEAD);
#pragma unroll
      for (int p = 0; p < 8; ++p) kx[p] = s4[p * 256 + tid];
#pragma unroll
      for (int p = 0; p < 8; ++p) {
        int idx4 = p * 256 + tid;
        int kv = (idx4 >> 2) & 63, d4 = (idx4 & 3) | ((idx4 >> 8) << 2);
        vx[p] = sv[kv * 32 + d4];
      }
    }
    __syncthreads();                       // staging visible

    f32x4 sacc[4];
#pragma unroll
    for (int mt = 0; mt < 4; ++mt) sacc[mt] = zero4;
    __builtin_amdgcn_s_setprio(1);
#pragma unroll
    for (int mt = 0; mt < 4; ++mt) {
      const int row = mt * 16 + lr;
      const int rbase = row * 128;
      const int sw = (row & 7) << 3;
#pragma unroll
      for (int kc = 0; kc < 4; ++kc) {
        const int doff = (kc * 32 + lg * 8) ^ sw;
        u16x8 kfh = *(const u16x8*)&khi[rbase + doff];
        u16x8 kfl = *(const u16x8*)&klo[rbase + doff];
        sacc[mt] = __builtin_amdgcn_mfma_f32_16x16x32_bf16(
            as_bf(kfh), as_bf(qh[kc]), sacc[mt], 0, 0, 0);
        sacc[mt] = __builtin_amdgcn_mfma_f32_16x16x32_bf16(
            as_bf(kfh), as_bf(qlo[kc]), sacc[mt], 0, 0, 0);
        sacc[mt] = __builtin_amdgcn_mfma_f32_16x16x32_bf16(
            as_bf(kfl), as_bf(qh[kc]), sacc[mt], 0, 0, 0);
      }
    }
    __builtin_amdgcn_s_setprio(0);
    __syncthreads();                       // all klo reads done before pwb writes

    // softmax + direct p_attn store + bf16 P into pwb
    const int swp = (lr & 7) << 3;
#pragma unroll
    for (int mt = 0; mt < 4; ++mt) {
      f32x4 pv;
#pragma unroll
      for (int r = 0; r < 4; ++r) pv[r] = __expf(sacc[mt][r] - m) * invl;
      *(f32x4*)&Prow[kt * KT + mt * 16 + lg * 4] = pv;   // 64B-coalesced
      u16x4 pb;
#pragma unroll
      for (int r = 0; r < 4; ++r) pb[r] = bfr(pv[r]);
      *(u16x4*)&pwb[lr * 64 + ((mt * 16 + lg * 4) ^ swp)] = pb;
    }

    u16x8 pf[2];
    pf[0] = *(const u16x8*)&pwb[lr * 64 + ((lg * 8) ^ swp)];
    pf[1] = *(const u16x8*)&pwb[lr * 64 + ((32 + lg * 8) ^ swp)];

    __builtin_amdgcn_s_setprio(1);
#pragma unroll
    for (int dt = 0; dt < 8; ++dt) {
      const int rbase = (dt * 16 + lr) * 64;
#pragma unroll
      for (int kvc = 0; kvc < 2; ++kvc) {
        u16x8 vf = *(const u16x8*)&vtr[rbase + ((kvc * 32 + lg * 8) ^ swp)];
        oacc[dt] = __builtin_amdgcn_mfma_f32_16x16x32_bf16(
            as_bf(pf[kvc]), as_bf(vf), oacc[dt], 0, 0, 0);
      }
    }
    __builtin_amdgcn_s_setprio(0);
  }

  // ---- epilogue: p_val ----
#pragma unroll
  for (int dt = 0; dt < 8; ++dt) {
#pragma unroll
    for (int r = 0; r < 4; ++r) {
      const int qloc = w * 16 + lg * 4 + r;
      Ov[(size_t)(qb * BM + qloc) * DHEAD + dt * 16 + lr] = oacc[dt][r];
    }
  }
}

extern "C" void kernel_launch(void* const* d_in, const int* in_sizes, int n_in,
                              void* d_out, int out_size, void* d_ws,
                              size_t ws_size, hipStream_t stream) {
  const float* Q = (const float*)d_in[0];
  const float* K = (const float*)d_in[1];
  const float* V = (const float*)d_in[2];
  float* out = (float*)d_out;
  (void)in_sizes; (void)n_in; (void)out_size; (void)d_ws; (void)ws_size;
  dim3 grid(NH * (S_LEN / BM));  // 1024
  attn_kernel<<<grid, 256, 0, stream>>>(Q, K, V, out);
}

// Round 4
// 453.065 us; speedup vs baseline: 2.1808x; 2.1808x over previous
//
#include <hip/hip_runtime.h>
#include <hip/hip_bf16.h>
#include <math.h>

#define S_LEN 2048
#define DHEAD 128
#define NH    32          // B*H
#define BM    128         // q rows per workgroup (8 waves x 16)
#define KT    32          // kv rows per tile
#define NKT   (S_LEN / KT)   // 64
#define SCALE 0.08838834764831845f   // 1/sqrt(128)

typedef __attribute__((ext_vector_type(4))) float f32x4;
typedef __attribute__((ext_vector_type(8))) unsigned short u16x8;
typedef __attribute__((ext_vector_type(4))) unsigned short u16x4;
typedef __attribute__((ext_vector_type(8))) __bf16 bf16x8;

static __device__ __forceinline__ unsigned short bfr(float x) {
  __bf16 h = (__bf16)x;
  return __builtin_bit_cast(unsigned short, h);
}
static __device__ __forceinline__ float bup(unsigned short h) {
  return (float)__builtin_bit_cast(__bf16, h);
}
static __device__ __forceinline__ bf16x8 as_bf(u16x8 x) {
  return __builtin_bit_cast(bf16x8, x);
}

__global__ __launch_bounds__(512) void attn_kernel(
    const float* __restrict__ Qg, const float* __restrict__ Kg,
    const float* __restrict__ Vg, float* __restrict__ out) {
  // double-buffered tiles: 48 KB total
  __shared__ unsigned short khi[2][KT * DHEAD];   // 2 x 8 KB
  __shared__ unsigned short klo[2][KT * DHEAD];   // 2 x 8 KB
  __shared__ unsigned short vtr[2][DHEAD * KT];   // 2 x 8 KB (V transposed)

  const int tid = threadIdx.x;
  const int w  = tid >> 6;   // 0..7
  const int l  = tid & 63;
  const int lr = l & 15;
  const int lg = l >> 4;

  // XCD-aware decode: 16 q-blocks of a head on one XCD
  const int d_  = blockIdx.x;          // 0..511
  const int xcd = d_ & 7;
  const int slot = d_ >> 3;            // 0..63
  const int bh = xcd + 8 * (slot >> 4);
  const int qb = slot & 15;

  const size_t head_off = (size_t)bh * S_LEN * DHEAD;
  const float* Qh = Qg + head_off;
  const float* Kh = Kg + head_off;
  const float* Vh = Vg + head_off;
  float* Ov = out + head_off;
  float* Pa = out + (size_t)NH * S_LEN * DHEAD + (size_t)bh * S_LEN * S_LEN;

  const int swk = (lr & 7) << 3;       // khi/klo read swizzle (row&7 == lr&7)

  // ---- staging lambdas: all registers die inside; no liveness across barriers
  auto stage_k = [&](int kt, int b, bool lo_too) {
    const float4* s4 = (const float4*)(Kh + (size_t)kt * KT * DHEAD);
#pragma unroll
    for (int p = 0; p < 2; ++p) {
      int idx4 = p * 512 + tid;          // 1024 float4 per tile
      int kv = idx4 >> 5, d4 = idx4 & 31;
      float4 v = s4[idx4];
      float f[4] = {v.x, v.y, v.z, v.w};
      int off = kv * 128 + ((d4 * 4) ^ ((kv & 7) << 3));
      u16x4 hi, lo;
#pragma unroll
      for (int j = 0; j < 4; ++j) {
        unsigned short h = bfr(f[j]);
        hi[j] = h;
        lo[j] = bfr(f[j] - bup(h));
      }
      *(u16x4*)&khi[b][off] = hi;
      if (lo_too) *(u16x4*)&klo[b][off] = lo;
    }
  };
  auto stage_v = [&](int kt, int b) {
    const float4* s4 = (const float4*)(Vh + (size_t)kt * KT * DHEAD);
#pragma unroll
    for (int p = 0; p < 2; ++p) {
      int idx4 = p * 512 + tid;
      int kv = (idx4 >> 2) & 31;
      int d4 = (idx4 & 3) | ((idx4 >> 7) << 2);
      float4 v = s4[kv * 32 + d4];       // 64B-coalesced per 4 lanes
      float f[4] = {v.x, v.y, v.z, v.w};
#pragma unroll
      for (int j = 0; j < 4; ++j) {
        int d = d4 * 4 + j;
        vtr[b][d * 32 + (kv ^ (((d >> 1) & 3) << 3))] = bfr(f[j]);
      }
    }
  };

  // ---- Q fragments (B-operand of S^T = K·Q^T), pre-scaled, hi/lo split ----
  const int qrow = qb * BM + w * 16 + lr;
  const float* qptr = Qh + (size_t)qrow * DHEAD;
  u16x8 qh[4], qlo[4];
#pragma unroll
  for (int kc = 0; kc < 4; ++kc) {
    const float4* qp4 = (const float4*)(qptr + kc * 32 + lg * 8);
    float4 a = qp4[0], b = qp4[1];
    float xs[8] = {a.x, a.y, a.z, a.w, b.x, b.y, b.z, b.w};
#pragma unroll
    for (int i = 0; i < 8; ++i) {
      float x = xs[i] * SCALE;
      unsigned short h = bfr(x);
      qh[kc][i] = h;
      qlo[kc][i] = bfr(x - bup(h));
    }
  }

  const f32x4 zero4 = {0.f, 0.f, 0.f, 0.f};
  float m = -INFINITY, lsum = 0.f;

  // ================= phase 1: running row max & sum (hi-only QK) ===========
  stage_k(0, 0, false);
  for (int kt = 0; kt < NKT; ++kt) {
    __syncthreads();                     // stage(kt) visible; buf[kt^1] free
    if (kt + 1 < NKT) stage_k(kt + 1, (kt + 1) & 1, false);
    const int cur = kt & 1;

    f32x4 sacc0 = zero4, sacc1 = zero4;
    __builtin_amdgcn_s_setprio(1);
#pragma unroll
    for (int kc = 0; kc < 4; ++kc) {
      const int doff = (kc * 32 + lg * 8) ^ swk;
      u16x8 k0 = *(const u16x8*)&khi[cur][lr * 128 + doff];
      u16x8 k1 = *(const u16x8*)&khi[cur][(16 + lr) * 128 + doff];
      sacc0 = __builtin_amdgcn_mfma_f32_16x16x32_bf16(
          as_bf(k0), as_bf(qh[kc]), sacc0, 0, 0, 0);
      sacc1 = __builtin_amdgcn_mfma_f32_16x16x32_bf16(
          as_bf(k1), as_bf(qh[kc]), sacc1, 0, 0, 0);
    }
    __builtin_amdgcn_s_setprio(0);

    float tmax = sacc0[0];
#pragma unroll
    for (int r = 0; r < 4; ++r) tmax = fmaxf(fmaxf(tmax, sacc0[r]), sacc1[r]);
    tmax = fmaxf(tmax, __shfl_xor(tmax, 16));
    tmax = fmaxf(tmax, __shfl_xor(tmax, 32));
    float mnew = fmaxf(m, tmax);
    float esum = 0.f;
#pragma unroll
    for (int r = 0; r < 4; ++r)
      esum += __expf(sacc0[r] - mnew) + __expf(sacc1[r] - mnew);
    esum += __shfl_xor(esum, 16);
    esum += __shfl_xor(esum, 32);
    lsum = lsum * __expf(m - mnew) + esum;
    m = mnew;
  }
  const float invl = 1.0f / lsum;

  // ================= phase 2: recompute (split), write P, PV ===============
  f32x4 oacc[8];
#pragma unroll
  for (int dt = 0; dt < 8; ++dt) oacc[dt] = zero4;

  float* Prow = Pa + (size_t)(qb * BM + w * 16 + lr) * S_LEN;

  stage_k(0, 0, true);
  stage_v(0, 0);
  for (int kt = 0; kt < NKT; ++kt) {
    __syncthreads();
    if (kt + 1 < NKT) {
      stage_k(kt + 1, (kt + 1) & 1, true);
      stage_v(kt + 1, (kt + 1) & 1);
    }
    const int cur = kt & 1;

    f32x4 sacc0 = zero4, sacc1 = zero4;
    __builtin_amdgcn_s_setprio(1);
#pragma unroll
    for (int kc = 0; kc < 4; ++kc) {
      const int doff = (kc * 32 + lg * 8) ^ swk;
      u16x8 kh0 = *(const u16x8*)&khi[cur][lr * 128 + doff];
      u16x8 kl0 = *(const u16x8*)&klo[cur][lr * 128 + doff];
      u16x8 kh1 = *(const u16x8*)&khi[cur][(16 + lr) * 128 + doff];
      u16x8 kl1 = *(const u16x8*)&klo[cur][(16 + lr) * 128 + doff];
      sacc0 = __builtin_amdgcn_mfma_f32_16x16x32_bf16(
          as_bf(kh0), as_bf(qh[kc]), sacc0, 0, 0, 0);
      sacc0 = __builtin_amdgcn_mfma_f32_16x16x32_bf16(
          as_bf(kh0), as_bf(qlo[kc]), sacc0, 0, 0, 0);
      sacc0 = __builtin_amdgcn_mfma_f32_16x16x32_bf16(
          as_bf(kl0), as_bf(qh[kc]), sacc0, 0, 0, 0);
      sacc1 = __builtin_amdgcn_mfma_f32_16x16x32_bf16(
          as_bf(kh1), as_bf(qh[kc]), sacc1, 0, 0, 0);
      sacc1 = __builtin_amdgcn_mfma_f32_16x16x32_bf16(
          as_bf(kh1), as_bf(qlo[kc]), sacc1, 0, 0, 0);
      sacc1 = __builtin_amdgcn_mfma_f32_16x16x32_bf16(
          as_bf(kl1), as_bf(qh[kc]), sacc1, 0, 0, 0);
    }
    __builtin_amdgcn_s_setprio(0);

    // softmax: lane (lr,lg) reg r holds P[q=w*16+lr][kv = kt*32 + {lg*4+r | 16+lg*4+r}]
    f32x4 pv0, pv1;
#pragma unroll
    for (int r = 0; r < 4; ++r) {
      pv0[r] = __expf(sacc0[r] - m) * invl;
      pv1[r] = __expf(sacc1[r] - m) * invl;
    }
    // direct p_attn stores: 4 lanes (lg) cover 64B contiguous per q-row
    *(f32x4*)&Prow[kt * KT + lg * 4] = pv0;
    *(f32x4*)&Prow[kt * KT + 16 + lg * 4] = pv1;

    // PV A-fragment: lane needs P[lr][kv=lg*8+j], j=0..7.
    // Source lane (lg'=(lg&1)*2+(j>>2))*16+lr holds it in pv0 (kv<16) or pv1.
    // One shfl can't serve dests needing different halves from the same src,
    // so pack BOTH bf16 candidates into one u32 and let dest pick by its lg&2.
    u16x8 pf;
    {
      unsigned pk[4];
#pragma unroll
      for (int r = 0; r < 4; ++r)
        pk[r] = ((unsigned)bfr(pv1[r]) << 16) | (unsigned)bfr(pv0[r]);
      const int la = ((lg & 1) * 2) * 16 + lr;
      const int lb = la + 16;
      const bool hi = (lg & 2) != 0;
#pragma unroll
      for (int r = 0; r < 4; ++r) {
        unsigned ta = (unsigned)__shfl((int)pk[r], la, 64);
        unsigned tb = (unsigned)__shfl((int)pk[r], lb, 64);
        pf[r]     = (unsigned short)(hi ? (ta >> 16) : (ta & 0xffffu));
        pf[r + 4] = (unsigned short)(hi ? (tb >> 16) : (tb & 0xffffu));
      }
    }

    __builtin_amdgcn_s_setprio(1);
#pragma unroll
    for (int dt = 0; dt < 8; ++dt) {
      const int row = dt * 16 + lr;
      u16x8 vf = *(const u16x8*)&vtr[cur][row * 32 +
                                          ((lg * 8) ^ (((row >> 1) & 3) << 3))];
      oacc[dt] = __builtin_amdgcn_mfma_f32_16x16x32_bf16(
          as_bf(pf), as_bf(vf), oacc[dt], 0, 0, 0);
    }
    __builtin_amdgcn_s_setprio(0);
  }

  // ---- epilogue: p_val ----
#pragma unroll
  for (int dt = 0; dt < 8; ++dt) {
#pragma unroll
    for (int r = 0; r < 4; ++r) {
      const int qloc = w * 16 + lg * 4 + r;
      Ov[(size_t)(qb * BM + qloc) * DHEAD + dt * 16 + lr] = oacc[dt][r];
    }
  }
}

extern "C" void kernel_launch(void* const* d_in, const int* in_sizes, int n_in,
                              void* d_out, int out_size, void* d_ws,
                              size_t ws_size, hipStream_t stream) {
  const float* Q = (const float*)d_in[0];
  const float* K = (const float*)d_in[1];
  const float* V = (const float*)d_in[2];
  float* out = (float*)d_out;
  (void)in_sizes; (void)n_in; (void)out_size; (void)d_ws; (void)ws_size;
  dim3 grid(NH * (S_LEN / BM));  // 512
  attn_kernel<<<grid, 512, 0, stream>>>(Q, K, V, out);
}